// Round 2
// baseline (135.933 us; speedup 1.0000x reference)
//
#include <hip/hip_runtime.h>
#include <hip/hip_bf16.h>

// Problem constants (fixed by the reference setup)
constexpr int   kB    = 2048;    // rows in feats
constexpr int   kC    = 256;     // feature dim
constexpr int   kG    = 128;     // group size = topk * num_instances
constexpr int   kKg   = 128;     // number of label groups
constexpr int   kM    = kKg * kG; // 16384 rows of Fs
constexpr float kEps  = 1e-6f;
constexpr float kInvT = 20.0f;   // 1/0.05

constexpr int kNA = kB  * kC;    // 524288  feats elements
constexpr int kNB = kB * 8 * kC; // 4194304 feats_s elements

typedef short bf16x8 __attribute__((ext_vector_type(8)));   // 8 bf16 in 4 VGPRs
typedef float floatx4 __attribute__((ext_vector_type(4)));  // MFMA accumulator

__device__ __forceinline__ unsigned short bf16_rne(float x) {
    union { float f; unsigned int u; } c; c.f = x;
    unsigned int r = c.u + 0x7FFFu + ((c.u >> 16) & 1u);
    return (unsigned short)(r >> 16);
}

// Kernel 1: fp32 -> bf16 pre-convert (once), and zero pos_e/neg_e.
__global__ __launch_bounds__(256) void convert_kernel(
    const float* __restrict__ feats,    // [2048,256] fp32
    const float* __restrict__ feats_s,  // [16384,256] fp32
    __hip_bfloat16* __restrict__ fa,    // [2048,256] bf16 out
    __hip_bfloat16* __restrict__ fb,    // [16384,256] bf16 out
    float* __restrict__ zero_area)      // pos[2048], neg[2048]
{
    int gid = blockIdx.x * 256 + threadIdx.x;
    if (gid < 2 * kB) zero_area[gid] = 0.0f;

    size_t base = (size_t)gid * 8;
    const float* src; __hip_bfloat16* dst; size_t off;
    if (base < (size_t)kNA) { src = feats;   dst = fa; off = base; }
    else                    { src = feats_s; dst = fb; off = base - kNA; }
    float4 v0 = *(const float4*)(src + off);
    float4 v1 = *(const float4*)(src + off + 4);
    unsigned short u[8];
    u[0] = bf16_rne(v0.x); u[1] = bf16_rne(v0.y);
    u[2] = bf16_rne(v0.z); u[3] = bf16_rne(v0.w);
    u[4] = bf16_rne(v1.x); u[5] = bf16_rne(v1.y);
    u[6] = bf16_rne(v1.z); u[7] = bf16_rne(v1.w);
    *(uint4*)(dst + off) = *(const uint4*)u;
}

// Kernel 2 (R12 = R11 with LDS cut to the HW-verified 128 KiB):
// 256x256 tile per block, 8 waves (2x4) of 128x64 each, BK=64
// double-buffered LDS, cross-K-step register prefetch: global loads for
// step k+1 are issued BEFORE the barrier of step k and consumed (vmcnt)
// AFTER compute(k). XOR-swizzled LDS p = q^(r&7) on 16B chunks both
// sides (0 conflicts verified at the 128-row version; algebra unchanged).
// rmin/rmax are OVERLAID on As after the last compute (static LDS must
// stay at 128 KiB = the verified gfx950 envelope; 136 KiB failed to run).
// Retired levers (do NOT reintroduce):
//  - per-kk register prefetch inside the MFMA loop: spills (R5/R8/R9).
//  - permuted-lane global_load_lds: breaks DMA coalescing (R4: 10x slower).
//  - fused finalize w/ per-block __threadfence: +120 µs (R10).
__global__ __launch_bounds__(512) void sim_minmax_kernel(
    const __hip_bfloat16* __restrict__ fa,   // [2048,256] bf16
    const __hip_bfloat16* __restrict__ fb,   // [16384,256] bf16
    const int* __restrict__ labels,          // [2048]
    const int* __restrict__ labels_s,        // [16384]
    float* __restrict__ pos_e,               // [2048]
    float* __restrict__ neg_e)               // [2048]
{
    const int n0   = blockIdx.x * 256;   // col tile: 2 label groups
    const int row0 = blockIdx.y * 256;   // row tile

    // 64 KiB + 64 KiB = 128 KiB static LDS total.
    __shared__ alignas(16) __hip_bfloat16 As[2][256 * 64];
    __shared__ alignas(16) __hip_bfloat16 Bs[2][256 * 64];
    // Overlay (used only after all MFMA compute is done):
    float* rmin = (float*)&As[0][0];          // [256][4] = 4 KiB
    float* rmax = (float*)&As[0][0] + 1024;   // [256][4] = 4 KiB

    const int t    = threadIdx.x;
    const int wave = t >> 6;
    const int lane = t & 63;
    const int l15  = lane & 15;
    const int quad = lane >> 4;
    const int wm   = wave >> 2;   // row half (0..1): 128 rows
    const int wn   = wave & 3;    // col quarter (0..3): 64 cols

    floatx4 acc[8][4];
#pragma unroll
    for (int mt = 0; mt < 8; mt++)
#pragma unroll
        for (int nt = 0; nt < 4; nt++)
            acc[mt][nt] = (floatx4){0.f, 0.f, 0.f, 0.f};

    // In-flight staging registers (live across one compute phase).
    uint4 areg[4], breg[4];

    auto stage_load = [&](int k0) {
#pragma unroll
        for (int rep = 0; rep < 4; rep++) {
            int c = t + 512 * rep;         // 0..2047 16B chunks
            int r = c >> 3, q = c & 7;     // r: 0..255 rows, q: chunk in row
            areg[rep] = *(const uint4*)(fa + (size_t)(row0 + r) * kC + k0 + q * 8);
            breg[rep] = *(const uint4*)(fb + (size_t)(n0   + r) * kC + k0 + q * 8);
        }
    };
    auto stage_write = [&](int bi) {
#pragma unroll
        for (int rep = 0; rep < 4; rep++) {
            int c = t + 512 * rep;
            int r = c >> 3, q = c & 7;
            int p = (q ^ (r & 7)) * 8;     // XOR swizzle, bijective per row
            *(uint4*)(&As[bi][r * 64 + p]) = areg[rep];
            *(uint4*)(&Bs[bi][r * 64 + p]) = breg[rep];
        }
    };
    auto compute = [&](int bi) {
#pragma unroll
        for (int kk = 0; kk < 64; kk += 32) {
            const int kc = kk >> 3;                        // chunk base 0 or 4
            const int pc = ((kc + quad) ^ (l15 & 7)) * 8;  // swizzled offset
            bf16x8 a[8], b[4];
#pragma unroll
            for (int mt = 0; mt < 8; mt++)
                a[mt] = *(const bf16x8*)(&As[bi][(wm * 128 + mt * 16 + l15) * 64 + pc]);
#pragma unroll
            for (int nt = 0; nt < 4; nt++)
                b[nt] = *(const bf16x8*)(&Bs[bi][(wn * 64 + nt * 16 + l15) * 64 + pc]);
            __builtin_amdgcn_s_setprio(1);
#pragma unroll
            for (int mt = 0; mt < 8; mt++)
#pragma unroll
                for (int nt = 0; nt < 4; nt++)
                    acc[mt][nt] = __builtin_amdgcn_mfma_f32_16x16x32_bf16(
                        a[mt], b[nt], acc[mt][nt], 0, 0, 0);
            __builtin_amdgcn_s_setprio(0);
        }
    };

    // K = 256 = 4 steps of BK=64, double-buffered, one barrier per step.
    // write(k+1) sits AFTER compute(k): the vmcnt wait for its regs lands
    // a full compute phase after the loads were issued.
    stage_load(0);
    stage_write(0);
    stage_load(64);
    __syncthreads();
    compute(0);
    stage_write(1);
    stage_load(128);
    __syncthreads();
    compute(1);
    stage_write(0);
    stage_load(192);
    __syncthreads();
    compute(0);
    stage_write(1);
    __syncthreads();
    compute(1);
    __syncthreads();   // all MFMA reads done before the rmin/rmax overlay

    // Per-row min/max over this wave's 64 columns.
    // D layout: col = lane&15, row = quad*4 + reg within each 16x16 tile.
#pragma unroll
    for (int mt = 0; mt < 8; mt++) {
#pragma unroll
        for (int reg = 0; reg < 4; reg++) {
            float vn = fminf(fminf(acc[mt][0][reg], acc[mt][1][reg]),
                             fminf(acc[mt][2][reg], acc[mt][3][reg]));
            float vx = fmaxf(fmaxf(acc[mt][0][reg], acc[mt][1][reg]),
                             fmaxf(acc[mt][2][reg], acc[mt][3][reg]));
#pragma unroll
            for (int s = 1; s < 16; s <<= 1) {
                vn = fminf(vn, __shfl_xor(vn, s, 64));
                vx = fmaxf(vx, __shfl_xor(vx, s, 64));
            }
            if (l15 == 0) {
                int r = wm * 128 + mt * 16 + quad * 4 + reg;
                rmin[r * 4 + wn] = vn;
                rmax[r * 4 + wn] = vx;
            }
        }
    }
    __syncthreads();

    // 512 threads: r = row (0..255), h = which label group (0..1).
    {
        int r = t & 255;
        int h = t >> 8;
        float mn = fminf(rmin[r * 4 + 2 * h], rmin[r * 4 + 2 * h + 1]);
        float mx = fmaxf(rmax[r * 4 + 2 * h], rmax[r * 4 + 2 * h + 1]);
        int gb  = row0 + r;
        int grp = blockIdx.x * 2 + h;
        int gn0 = grp * kG;
        if (labels[gb] == labels_s[gn0]) {
            pos_e[gb] = __expf(mn * kInvT);            // unique writer per row
        } else {
            atomicAdd(&neg_e[gb], __expf(mx * kInvT));
        }
    }
}

// Kernel 3: per-row loss + mean over 2048 rows -> single fp32 scalar.
__global__ void finalize_kernel(const float* __restrict__ pos_e,
                                const float* __restrict__ neg_e,
                                float* __restrict__ out)
{
    __shared__ float red[256];
    float s = 0.f;
    for (int r = threadIdx.x; r < kB; r += 256) {
        float p = pos_e[r];
        float n = neg_e[r];
        s += -__logf(p / (p + n + kEps) + kEps);
    }
    red[threadIdx.x] = s;
    __syncthreads();
    for (int off = 128; off > 0; off >>= 1) {
        if (threadIdx.x < off) red[threadIdx.x] += red[threadIdx.x + off];
        __syncthreads();
    }
    if (threadIdx.x == 0) out[0] = red[0] / (float)kB;
}

extern "C" void kernel_launch(void* const* d_in, const int* in_sizes, int n_in,
                              void* d_out, int out_size, void* d_ws, size_t ws_size,
                              hipStream_t stream) {
    (void)in_sizes; (void)n_in; (void)out_size; (void)ws_size;

    const float* feats    = (const float*)d_in[0];
    const float* feats_s  = (const float*)d_in[1];
    const int*   labels   = (const int*)d_in[2];
    const int*   labels_s = (const int*)d_in[3];
    // d_in[4] = topk (8), d_in[5] = num_instances (16) — fixed, hard-coded.

    // ws layout: pos[2048] f32 | neg[2048] f32 | pad | fa 1MB | fb 8MB
    float* pos_e = (float*)d_ws;
    float* neg_e = pos_e + kB;
    __hip_bfloat16* fa = (__hip_bfloat16*)((char*)d_ws + 32768);
    __hip_bfloat16* fb = (__hip_bfloat16*)((char*)d_ws + 32768 + (size_t)kNA * 2);

    // convert: (kNA + kNB)/8 threads = 589824 -> 2304 blocks of 256
    convert_kernel<<<(kNA + kNB) / 8 / 256, 256, 0, stream>>>(
        feats, feats_s, fa, fb, pos_e);

    dim3 grid(kM / 256, kB / 256);   // 64 col-tiles x 8 row-tiles = 512 blocks
    sim_minmax_kernel<<<grid, 512, 0, stream>>>(
        fa, fb, labels, labels_s, pos_e, neg_e);
    finalize_kernel<<<1, 256, 0, stream>>>(pos_e, neg_e, (float*)d_out);
}

// Round 3
// 119.078 us; speedup vs baseline: 1.1415x; 1.1415x over previous
//
#include <hip/hip_runtime.h>
#include <hip/hip_bf16.h>

// Problem constants (fixed by the reference setup)
constexpr int   kB    = 2048;    // rows in feats
constexpr int   kC    = 256;     // feature dim
constexpr int   kG    = 128;     // group size = topk * num_instances
constexpr int   kKg   = 128;     // number of label groups
constexpr float kEps  = 1e-6f;
constexpr float kInvT = 20.0f;   // 1/0.05

constexpr int kNA = kB  * kC;    // 524288  feats elements
constexpr int kNB = kB * 8 * kC; // 4194304 feats_s elements

typedef short bf16x8 __attribute__((ext_vector_type(8)));   // 8 bf16 in 4 VGPRs
typedef float floatx4 __attribute__((ext_vector_type(4)));  // MFMA accumulator

__device__ __forceinline__ unsigned short bf16_rne(float x) {
    union { float f; unsigned int u; } c; c.f = x;
    unsigned int r = c.u + 0x7FFFu + ((c.u >> 16) & 1u);
    return (unsigned short)(r >> 16);
}

// Direct global -> LDS DMA, 16 B per lane. LDS dest is wave-uniform base +
// lane*16 (HW semantics); global src is per-lane.
__device__ __forceinline__ void gload_lds16(const __hip_bfloat16* g,
                                            __hip_bfloat16* l) {
    __builtin_amdgcn_global_load_lds(
        (const __attribute__((address_space(1))) unsigned int*)g,
        (__attribute__((address_space(3))) unsigned int*)l, 16, 0, 0);
}

// Kernel 1: fp32 -> bf16 pre-convert (once), and zero pos_e/neg_e.
__global__ __launch_bounds__(256) void convert_kernel(
    const float* __restrict__ feats,    // [2048,256] fp32
    const float* __restrict__ feats_s,  // [16384,256] fp32
    __hip_bfloat16* __restrict__ fa,    // [2048,256] bf16 out
    __hip_bfloat16* __restrict__ fb,    // [16384,256] bf16 out
    float* __restrict__ zero_area)      // pos[2048], neg[2048]
{
    int gid = blockIdx.x * 256 + threadIdx.x;
    if (gid < 2 * kB) zero_area[gid] = 0.0f;

    size_t base = (size_t)gid * 8;
    const float* src; __hip_bfloat16* dst; size_t off;
    if (base < (size_t)kNA) { src = feats;   dst = fa; off = base; }
    else                    { src = feats_s; dst = fb; off = base - kNA; }
    float4 v0 = *(const float4*)(src + off);
    float4 v1 = *(const float4*)(src + off + 4);
    unsigned short u[8];
    u[0] = bf16_rne(v0.x); u[1] = bf16_rne(v0.y);
    u[2] = bf16_rne(v0.z); u[3] = bf16_rne(v0.w);
    u[4] = bf16_rne(v1.x); u[5] = bf16_rne(v1.y);
    u[6] = bf16_rne(v1.z); u[7] = bf16_rne(v1.w);
    *(uint4*)(dst + off) = *(const uint4*)u;
}

// Kernel 2 (R13): R7's verified 128x128 structure (2048 blocks, 4 waves of
// 64x64, 34 KB LDS -> 4 blocks/CU) with ONE change: staging goes through
// linear global_load_lds dwordx4 (m97-exact: lane-ascending global src,
// linear row-major [128][64] LDS). No staging VGPRs, no ds_write VALU.
// Linear LDS reads carry a known ~4 cyc/ds_read bank conflict (m97/m98
// precedent: 1.7e7 conflict cycles at 874 TF) — accepted.
// Retired levers (do NOT reintroduce):
//  - 256x256 tile / 128KB LDS: occupancy collapse to 1 block/CU, 60 µs (R12).
//  - per-kk register prefetch inside the MFMA loop: spills (R5/R8/R9).
//  - permuted-lane global_load_lds: breaks DMA coalescing (R4: 10x slower).
//  - fused finalize w/ per-block __threadfence: +120 µs (R10 isolated).
__global__ __launch_bounds__(256) void sim_minmax_kernel(
    const __hip_bfloat16* __restrict__ fa,   // [2048,256] bf16
    const __hip_bfloat16* __restrict__ fb,   // [16384,256] bf16
    const int* __restrict__ labels,          // [2048]
    const int* __restrict__ labels_s,        // [16384]
    float* __restrict__ pos_e,               // [2048]
    float* __restrict__ neg_e)               // [2048]
{
    const int group = blockIdx.x;        // 0..127
    const int row0  = blockIdx.y * 128;  // 0..2047 step 128
    const int n0    = group * kG;        // base row in Fs / labels_s

    __shared__ alignas(16) __hip_bfloat16 As[128 * 64];  // linear [128][64]
    __shared__ alignas(16) __hip_bfloat16 Bs[128 * 64];  // linear [128][64]
    __shared__ float rmin[128][2];
    __shared__ float rmax[128][2];

    const int t    = threadIdx.x;
    const int wave = t >> 6;
    const int lane = t & 63;
    const int l15  = lane & 15;
    const int quad = lane >> 4;
    const int wm   = wave >> 1;   // row half (0..1)
    const int wn   = wave & 1;    // col half (0..1)

    floatx4 acc[4][4];
#pragma unroll
    for (int mt = 0; mt < 4; mt++)
#pragma unroll
        for (int nt = 0; nt < 4; nt++)
            acc[mt][nt] = (floatx4){0.f, 0.f, 0.f, 0.f};

    for (int k0 = 0; k0 < kC; k0 += 64) {
        // Stage A and B tiles: 1024 16B chunks each, chunk c = t + 256*rep.
        // LDS chunk c sits at As[c*8] (row r = c>>3, col chunk q = c&7) —
        // exactly base(wave-uniform) + lane*16, so the DMA lands linearly.
        // Global src: row (row0|n0)+r, bytes [k0 + q*8 .. +7] — each 8-lane
        // row-group covers one contiguous 128B segment (coalesced).
#pragma unroll
        for (int rep = 0; rep < 4; rep++) {
            int c = t + 256 * rep, r = c >> 3, q = c & 7;
            int cbase = (t & ~63) + 256 * rep;   // wave-uniform chunk base
            gload_lds16(fa + (size_t)(row0 + r) * kC + k0 + q * 8,
                        &As[cbase * 8]);
            gload_lds16(fb + (size_t)(n0 + r) * kC + k0 + q * 8,
                        &Bs[cbase * 8]);
        }
        __syncthreads();

#pragma unroll
        for (int kk = 0; kk < 64; kk += 32) {
            bf16x8 a[4], b[4];
#pragma unroll
            for (int mt = 0; mt < 4; mt++)
                a[mt] = *(const bf16x8*)(&As[(wm * 64 + mt * 16 + l15) * 64 + kk + quad * 8]);
#pragma unroll
            for (int nt = 0; nt < 4; nt++)
                b[nt] = *(const bf16x8*)(&Bs[(wn * 64 + nt * 16 + l15) * 64 + kk + quad * 8]);
            __builtin_amdgcn_s_setprio(1);
#pragma unroll
            for (int mt = 0; mt < 4; mt++)
#pragma unroll
                for (int nt = 0; nt < 4; nt++)
                    acc[mt][nt] = __builtin_amdgcn_mfma_f32_16x16x32_bf16(
                        a[mt], b[nt], acc[mt][nt], 0, 0, 0);
            __builtin_amdgcn_s_setprio(0);
        }
        __syncthreads();
    }

    // Per-row min/max over this wave's 64 columns.
    // D layout: col = lane&15, row = quad*4 + reg within each 16x16 tile.
#pragma unroll
    for (int mt = 0; mt < 4; mt++) {
#pragma unroll
        for (int reg = 0; reg < 4; reg++) {
            float vn = fminf(fminf(acc[mt][0][reg], acc[mt][1][reg]),
                             fminf(acc[mt][2][reg], acc[mt][3][reg]));
            float vx = fmaxf(fmaxf(acc[mt][0][reg], acc[mt][1][reg]),
                             fmaxf(acc[mt][2][reg], acc[mt][3][reg]));
#pragma unroll
            for (int s = 1; s < 16; s <<= 1) {
                vn = fminf(vn, __shfl_xor(vn, s, 64));
                vx = fmaxf(vx, __shfl_xor(vx, s, 64));
            }
            if (l15 == 0) {
                int r = wm * 64 + mt * 16 + quad * 4 + reg;
                rmin[r][wn] = vn;
                rmax[r][wn] = vx;
            }
        }
    }
    __syncthreads();

    if (t < 128) {
        float mn = fminf(rmin[t][0], rmin[t][1]);
        float mx = fmaxf(rmax[t][0], rmax[t][1]);
        int gb = row0 + t;
        if (labels[gb] == labels_s[n0]) {
            pos_e[gb] = __expf(mn * kInvT);            // unique writer per row
        } else {
            atomicAdd(&neg_e[gb], __expf(mx * kInvT));
        }
    }
}

// Kernel 3: per-row loss + mean over 2048 rows -> single fp32 scalar.
__global__ void finalize_kernel(const float* __restrict__ pos_e,
                                const float* __restrict__ neg_e,
                                float* __restrict__ out)
{
    __shared__ float red[256];
    float s = 0.f;
    for (int r = threadIdx.x; r < kB; r += 256) {
        float p = pos_e[r];
        float n = neg_e[r];
        s += -__logf(p / (p + n + kEps) + kEps);
    }
    red[threadIdx.x] = s;
    __syncthreads();
    for (int off = 128; off > 0; off >>= 1) {
        if (threadIdx.x < off) red[threadIdx.x] += red[threadIdx.x + off];
        __syncthreads();
    }
    if (threadIdx.x == 0) out[0] = red[0] / (float)kB;
}

extern "C" void kernel_launch(void* const* d_in, const int* in_sizes, int n_in,
                              void* d_out, int out_size, void* d_ws, size_t ws_size,
                              hipStream_t stream) {
    (void)in_sizes; (void)n_in; (void)out_size; (void)ws_size;

    const float* feats    = (const float*)d_in[0];
    const float* feats_s  = (const float*)d_in[1];
    const int*   labels   = (const int*)d_in[2];
    const int*   labels_s = (const int*)d_in[3];
    // d_in[4] = topk (8), d_in[5] = num_instances (16) — fixed, hard-coded.

    // ws layout: pos[2048] f32 | neg[2048] f32 | pad | fa 1MB | fb 8MB
    float* pos_e = (float*)d_ws;
    float* neg_e = pos_e + kB;
    __hip_bfloat16* fa = (__hip_bfloat16*)((char*)d_ws + 32768);
    __hip_bfloat16* fb = (__hip_bfloat16*)((char*)d_ws + 32768 + (size_t)kNA * 2);

    // convert: (kNA + kNB)/8 threads = 589824 -> 2304 blocks of 256
    convert_kernel<<<(kNA + kNB) / 8 / 256, 256, 0, stream>>>(
        feats, feats_s, fa, fb, pos_e);

    dim3 grid(kKg, kB / 128);   // 128 groups x 16 row-tiles = 2048 blocks
    sim_minmax_kernel<<<grid, 256, 0, stream>>>(
        fa, fb, labels, labels_s, pos_e, neg_e);
    finalize_kernel<<<1, 256, 0, stream>>>(pos_e, neg_e, (float*)d_out);
}